// Round 12
// baseline (1245.571 us; speedup 1.0000x reference)
//
#include <hip/hip_runtime.h>
#include <hip/hip_bf16.h>
#include <cstddef>
#include <cstdint>

#define NN 2048      // nodes
#define CIN 2
#define HH 32
#define EMB 16
#define HOR 12
#define BB 32
#define TT 16
#define GC 128
#define XCOLS 1024
#define HCOLS 1024
#define CSZ ((size_t)NN * HCOLS)

typedef __attribute__((ext_vector_type(8))) _Float16 f16x8;
typedef __attribute__((ext_vector_type(16))) float f32x16;

// ---------------------------------------------------------------------------
// Kernel 1: A = softmax(relu(E1 @ E2^T)) -> A2 fp16 [row][k]
// ---------------------------------------------------------------------------
__global__ __launch_bounds__(256) void adj_softmax(const float* __restrict__ E1,
                                                   const float* __restrict__ E2,
                                                   _Float16* __restrict__ A2) {
    const int i = blockIdx.x;
    __shared__ float red[256];
    float e1[EMB];
#pragma unroll
    for (int k = 0; k < EMB; ++k) e1[k] = E1[i * EMB + k];

    float s[8];
    float mx = -1e30f;
#pragma unroll
    for (int q = 0; q < 8; ++q) {
        const int j = q * 256 + threadIdx.x;
        float d = 0.f;
#pragma unroll
        for (int k = 0; k < EMB; ++k) d += e1[k] * E2[j * EMB + k];
        d = fmaxf(d, 0.0f);
        s[q] = d;
        mx = fmaxf(mx, d);
    }
    red[threadIdx.x] = mx;
    __syncthreads();
    for (int off = 128; off > 0; off >>= 1) {
        if (threadIdx.x < off) red[threadIdx.x] = fmaxf(red[threadIdx.x], red[threadIdx.x + off]);
        __syncthreads();
    }
    mx = red[0];
    __syncthreads();

    float sum = 0.f;
#pragma unroll
    for (int q = 0; q < 8; ++q) { s[q] = expf(s[q] - mx); sum += s[q]; }
    red[threadIdx.x] = sum;
    __syncthreads();
    for (int off = 128; off > 0; off >>= 1) {
        if (threadIdx.x < off) red[threadIdx.x] += red[threadIdx.x + off];
        __syncthreads();
    }
    const float inv = 1.0f / red[0];
#pragma unroll
    for (int q = 0; q < 8; ++q)
        A2[(size_t)i * NN + q * 256 + threadIdx.x] = (_Float16)(s[q] * inv);
}

// ---------------------------------------------------------------------------
// Kernel 2: Bx[col][node] fp16 (single plane), col = (b*T+t)*C + c.
// ---------------------------------------------------------------------------
__global__ __launch_bounds__(256) void transpose_x(const float* __restrict__ x,
                                                   _Float16* __restrict__ Bx) {
    const int idx = blockIdx.x * 256 + threadIdx.x;
    const int col = idx >> 11;
    const int j   = idx & (NN - 1);
    const int bt  = col >> 1;
    const int c   = col & 1;
    Bx[(size_t)col * 2048 + j] = (_Float16)x[((size_t)bt * NN + j) * CIN + c];
}

// ---------------------------------------------------------------------------
// Kernel 3: x-path fp16 GEMM (32x32x16), single product, pipelined LDS dbuf.
// Block 128x128, 4 waves each 64x64 (2x2 accs of 32x32), BK=32, split-K=4.
// (r8 NPROD=1 structure - proven)
// ---------------------------------------------------------------------------
__global__ __launch_bounds__(256, 2) void gemm_x1(const _Float16* __restrict__ A2,
                                                  const _Float16* __restrict__ B2,
                                                  float* __restrict__ Cp) {
    constexpr int BUF = 16384;
    __shared__ char smem[2 * BUF];
    const int tid  = threadIdx.x;
    const int w    = tid >> 6;
    const int lane = tid & 63;
    const int m0 = blockIdx.y * 128;
    const int n0 = blockIdx.x * 128;
    const int k0 = blockIdx.z * 512;

    const _Float16 *gpa0, *gpa1, *gpb0, *gpb1;
    int lda0, lda1, ldb0, ldb1;
    {
        int cid, ko, row;
        cid = tid;       ko = cid >> 7; row = cid & 127;
        gpa0 = A2 + (size_t)(m0 + row) * 2048 + k0 + ko * 8;
        lda0 = ko * 2048 + row * 16;
        cid = tid + 256; ko = cid >> 7; row = cid & 127;
        gpa1 = A2 + (size_t)(m0 + row) * 2048 + k0 + ko * 8;
        lda1 = ko * 2048 + row * 16;
        cid = tid;       ko = cid >> 7; row = cid & 127;
        gpb0 = B2 + (size_t)(n0 + row) * 2048 + k0 + ko * 8;
        ldb0 = 8192 + ko * 2048 + row * 16;
        cid = tid + 256; ko = cid >> 7; row = cid & 127;
        gpb1 = B2 + (size_t)(n0 + row) * 2048 + k0 + ko * 8;
        ldb1 = 8192 + ko * 2048 + row * 16;
    }

    const int lrow = lane & 31, lg = lane >> 5;
    const int wr = (w >> 1) * 64;
    const int wc = (w & 1) * 64;
    const int aoff00 = (0 * 2 + lg) * 2048 + (wr +  0 + lrow) * 16;
    const int aoff01 = (1 * 2 + lg) * 2048 + (wr +  0 + lrow) * 16;
    const int aoff10 = (0 * 2 + lg) * 2048 + (wr + 32 + lrow) * 16;
    const int aoff11 = (1 * 2 + lg) * 2048 + (wr + 32 + lrow) * 16;
    const int boff00 = 8192 + (0 * 2 + lg) * 2048 + (wc +  0 + lrow) * 16;
    const int boff01 = 8192 + (1 * 2 + lg) * 2048 + (wc +  0 + lrow) * 16;
    const int boff10 = 8192 + (0 * 2 + lg) * 2048 + (wc + 32 + lrow) * 16;
    const int boff11 = 8192 + (1 * 2 + lg) * 2048 + (wc + 32 + lrow) * 16;

    f32x16 acc00 = (f32x16)(0.0f), acc01 = (f32x16)(0.0f);
    f32x16 acc10 = (f32x16)(0.0f), acc11 = (f32x16)(0.0f);

    uint4 Xa0, Xa1, Xb0, Xb1, Ya0, Ya1, Yb0, Yb1;

#define LOADSET(P)                                                             \
    P##a0 = *(const uint4*)gpa0; gpa0 += 32;                                   \
    P##a1 = *(const uint4*)gpa1; gpa1 += 32;                                   \
    P##b0 = *(const uint4*)gpb0; gpb0 += 32;                                   \
    P##b1 = *(const uint4*)gpb1; gpb1 += 32;

#define STORESET(P, SB)                                                        \
    *(uint4*)((SB) + lda0) = P##a0;                                            \
    *(uint4*)((SB) + lda1) = P##a1;                                            \
    *(uint4*)((SB) + ldb0) = P##b0;                                            \
    *(uint4*)((SB) + ldb1) = P##b1;

#define COMPUTE(BUFI) do {                                                     \
    const char* sb = smem + (BUFI) * BUF;                                      \
    f16x8 fa00 = *(const f16x8*)(sb + aoff00);                                 \
    f16x8 fa01 = *(const f16x8*)(sb + aoff01);                                 \
    f16x8 fa10 = *(const f16x8*)(sb + aoff10);                                 \
    f16x8 fa11 = *(const f16x8*)(sb + aoff11);                                 \
    f16x8 fb00 = *(const f16x8*)(sb + boff00);                                 \
    f16x8 fb01 = *(const f16x8*)(sb + boff01);                                 \
    f16x8 fb10 = *(const f16x8*)(sb + boff10);                                 \
    f16x8 fb11 = *(const f16x8*)(sb + boff11);                                 \
    acc00 = __builtin_amdgcn_mfma_f32_32x32x16_f16(fa00, fb00, acc00, 0, 0, 0);\
    acc01 = __builtin_amdgcn_mfma_f32_32x32x16_f16(fa00, fb10, acc01, 0, 0, 0);\
    acc10 = __builtin_amdgcn_mfma_f32_32x32x16_f16(fa10, fb00, acc10, 0, 0, 0);\
    acc11 = __builtin_amdgcn_mfma_f32_32x32x16_f16(fa10, fb10, acc11, 0, 0, 0);\
    acc00 = __builtin_amdgcn_mfma_f32_32x32x16_f16(fa01, fb01, acc00, 0, 0, 0);\
    acc01 = __builtin_amdgcn_mfma_f32_32x32x16_f16(fa01, fb11, acc01, 0, 0, 0);\
    acc10 = __builtin_amdgcn_mfma_f32_32x32x16_f16(fa11, fb01, acc10, 0, 0, 0);\
    acc11 = __builtin_amdgcn_mfma_f32_32x32x16_f16(fa11, fb11, acc11, 0, 0, 0);\
} while (0)

    LOADSET(X)
    LOADSET(Y)
#pragma unroll 1
    for (int it = 0; it < 16; it += 2) {
        STORESET(X, smem)
        __syncthreads();
        LOADSET(X)
        COMPUTE(0);
        STORESET(Y, smem + BUF)
        __syncthreads();
        LOADSET(Y)
        COMPUTE(1);
    }
#undef LOADSET
#undef STORESET
#undef COMPUTE

    float* Cs = Cp + (size_t)blockIdx.z * CSZ;
    const int col0 = n0 + wc + lrow;
#pragma unroll
    for (int r = 0; r < 16; ++r) {
        const int rp = (r & 3) + 8 * (r >> 2) + 4 * lg;
        Cs[(size_t)(m0 + wr + rp) * HCOLS + col0]           = acc00[r];
        Cs[(size_t)(m0 + wr + rp) * HCOLS + col0 + 32]      = acc01[r];
        Cs[(size_t)(m0 + wr + 32 + rp) * HCOLS + col0]      = acc10[r];
        Cs[(size_t)(m0 + wr + 32 + rp) * HCOLS + col0 + 32] = acc11[r];
    }
}

// ---------------------------------------------------------------------------
// Kernel 3b: AX = sum of 4 k-slice partials (one-time, x path)
// ---------------------------------------------------------------------------
__global__ __launch_bounds__(256) void reduce_ax(const float* __restrict__ P,
                                                 float* __restrict__ AX) {
    const size_t idx = (size_t)blockIdx.x * 256 + threadIdx.x;
    const float4* P4 = (const float4*)P;
    const size_t q = CSZ / 4;
    float4 a = P4[idx], b = P4[idx + q], c = P4[idx + 2 * q], d = P4[idx + 3 * q];
    float4 r;
    r.x = a.x + b.x + c.x + d.x;
    r.y = a.y + b.y + c.y + d.y;
    r.z = a.z + b.z + c.z + d.z;
    r.w = a.w + b.w + c.w + d.w;
    ((float4*)AX)[idx] = r;
}

// ---------------------------------------------------------------------------
// Kernel 3c: weight prep. Whr[k][h][g] = Wh[k][g*32+h]; Wxr[c][h][g]; bfold.
// ---------------------------------------------------------------------------
__global__ __launch_bounds__(256) void prep_weights(const float* __restrict__ Wx,
                                                    const float* __restrict__ bx,
                                                    const float* __restrict__ Wh,
                                                    const float* __restrict__ bh,
                                                    float* __restrict__ Whr,
                                                    float* __restrict__ Wxr,
                                                    float* __restrict__ bfold) {
    const int tid = threadIdx.x;
#pragma unroll
    for (int r = 0; r < 16; ++r) {
        const int idx = tid * 16 + r;
        const int k = idx >> 7, rem = idx & 127;
        const int h = rem >> 2, g = rem & 3;
        Whr[idx] = Wh[k * GC + g * HH + h];
    }
    {
        const int idx = tid;
        const int c = idx >> 7, rem = idx & 127;
        const int h = rem >> 2, g = rem & 3;
        Wxr[idx] = Wx[c * GC + g * HH + h];
    }
    if (tid < 128) {
        const int h = tid >> 2, g = tid & 3;
        bfold[tid] = bx[g * HH + h] + bh[g * HH + h];
    }
}

// ---------------------------------------------------------------------------
// Kernel 4: ONE fused step. 512 blocks; block bid = (my<<5)|(nx2<<1)|z.
// t>0 phase A: gemm tile rows my*128..+127, cols nx2*64..+63, K z*1024..+1023
//   -> P[z]; release-add flag[my][nx2]; relaxed-spin until z-partner done.
// phase B: gate for node slab (my*2+z)*64 (64 nodes), batches {2*nx2, 2*nx2+1}
//   = the block's OWN tile columns. c-state in global cst. hT ping-pong.
// ---------------------------------------------------------------------------
__global__ __launch_bounds__(256, 2) void fused_step(
        const _Float16* __restrict__ A2,
        const float* __restrict__ AX,
        float* __restrict__ P,
        const float* __restrict__ Whr,
        const float* __restrict__ Wxr,
        const float* __restrict__ bfold,
        float* __restrict__ cst,
        float* __restrict__ h32,
        const _Float16* __restrict__ hTr,
        _Float16* __restrict__ hTw,
        unsigned* __restrict__ flags,
        int t) {
    __shared__ char smem[24576];        // gemm dbuf 2x12KB; ah2[64][65] overlays
    __shared__ float whr[4096];
    __shared__ float wxr[256];
    __shared__ float bfl[128];

    const int tid = threadIdx.x;
    const int bid = blockIdx.x;
    const int z   = bid & 1;
    const int nx2 = (bid >> 1) & 15;
    const int my  = bid >> 5;
    const int m0 = my * 128, n0 = nx2 * 64, k0 = z * 1024;

    // ---- stage LSTM weights ----
#pragma unroll
    for (int r = 0; r < 4; ++r)
        *(float4*)&whr[tid * 4 + r * 1024] = *(const float4*)&Whr[tid * 4 + r * 1024];
    if (tid < 64) *(float4*)&wxr[tid * 4] = *(const float4*)&Wxr[tid * 4];
    if (tid < 32) *(float4*)&bfl[tid * 4] = *(const float4*)&bfold[tid * 4];
    __syncthreads();

    const int w = tid >> 6, lane = tid & 63;
    const int lrow = lane & 31, lg = lane >> 5;
    float* ah2 = (float*)smem;          // [64][65] fp32 after gemm

    if (t > 0) {
        // ---- phase A: gemm 128x64, K=1024, BK=32, 32 iters ----
        const int arow = tid & 127, apl = tid >> 7;
        const _Float16* gA0 = A2 + (size_t)(m0 + arow) * 2048 + k0 + apl * 8;
        const _Float16* gA1 = A2 + (size_t)(m0 + arow) * 2048 + k0 + (apl + 2) * 8;
        const int ldA0 = (apl * 128 + arow) * 16;
        const int ldA1 = ((apl + 2) * 128 + arow) * 16;
        const int bcol = tid & 63, bpl = tid >> 6;
        const _Float16* gB0 = hTr + (size_t)(n0 + bcol) * 2048 + k0 + bpl * 8;
        const int ldB0 = 8192 + (bpl * 64 + bcol) * 16;

        const int wr = (w >> 1) * 64;
        const int wc = (w & 1) * 32;
        int aoff[2][2], boff[2];
#pragma unroll
        for (int i = 0; i < 2; ++i)
#pragma unroll
            for (int ks = 0; ks < 2; ++ks)
                aoff[i][ks] = ((ks * 2 + lg) * 128 + wr + i * 32 + lrow) * 16;
#pragma unroll
        for (int ks = 0; ks < 2; ++ks)
            boff[ks] = 8192 + ((ks * 2 + lg) * 64 + wc + lrow) * 16;

        f32x16 acc0 = (f32x16)(0.0f), acc1 = (f32x16)(0.0f);
        uint4 Xa0, Xa1, Xb0, Ya0, Ya1, Yb0;

#define GLOAD(Q)                                                               \
    Q##a0 = *(const uint4*)gA0; gA0 += 32;                                     \
    Q##a1 = *(const uint4*)gA1; gA1 += 32;                                     \
    Q##b0 = *(const uint4*)gB0; gB0 += 32;
#define GSTORE(Q, SB)                                                          \
    *(uint4*)((SB) + ldA0) = Q##a0;                                            \
    *(uint4*)((SB) + ldA1) = Q##a1;                                            \
    *(uint4*)((SB) + ldB0) = Q##b0;
#define GCOMP(BUFI) do {                                                       \
    const char* sb = smem + (BUFI) * 12288;                                    \
    _Pragma("unroll") for (int ks = 0; ks < 2; ++ks) {                         \
        f16x8 fa0 = *(const f16x8*)(sb + aoff[0][ks]);                         \
        f16x8 fa1 = *(const f16x8*)(sb + aoff[1][ks]);                         \
        f16x8 fb  = *(const f16x8*)(sb + boff[ks]);                            \
        acc0 = __builtin_amdgcn_mfma_f32_32x32x16_f16(fa0, fb, acc0, 0, 0, 0); \
        acc1 = __builtin_amdgcn_mfma_f32_32x32x16_f16(fa1, fb, acc1, 0, 0, 0); \
    }                                                                          \
} while (0)

        GLOAD(X)
        GLOAD(Y)
#pragma unroll 1
        for (int it = 0; it < 32; it += 2) {
            GSTORE(X, smem)
            __syncthreads();
            if (it + 2 < 32) { GLOAD(X) }
            GCOMP(0);
            GSTORE(Y, smem + 12288)
            __syncthreads();
            if (it + 3 < 32) { GLOAD(Y) }
            GCOMP(1);
        }
#undef GLOAD
#undef GSTORE
#undef GCOMP

        float* Pz = P + (size_t)z * CSZ;
        const int col0 = n0 + wc + lrow;
#pragma unroll
        for (int r = 0; r < 16; ++r) {
            const int rp = (r & 3) + 8 * (r >> 2) + 4 * lg;
            Pz[(size_t)(m0 + wr + rp) * HCOLS + col0]      = acc0[r];
            Pz[(size_t)(m0 + wr + 32 + rp) * HCOLS + col0] = acc1[r];
        }
        __syncthreads();    // all stores issued & drained (vmcnt(0) at barrier)

        // ---- flag handshake with z-partner (release/relaxed-poll/acquire) --
        if (tid == 0) {
            unsigned* f = flags + (my * 16 + nx2) * 16;   // 64B-strided
            __hip_atomic_fetch_add(f, 1u, __ATOMIC_RELEASE, __HIP_MEMORY_SCOPE_AGENT);
            const unsigned target = 2u * (unsigned)t;
            unsigned spins = 0;
            while (__hip_atomic_load(f, __ATOMIC_RELAXED, __HIP_MEMORY_SCOPE_AGENT) < target
                   && spins < (1u << 22)) {
                __builtin_amdgcn_s_sleep(1);
                ++spins;
            }
            (void)__hip_atomic_load(f, __ATOMIC_ACQUIRE, __HIP_MEMORY_SCOPE_AGENT);
        }
        __syncthreads();

        // ---- stage ah2 = P[0]+P[1] for this block's gate slab --------------
        const int slab = my * 2 + z, n0g = slab * 64;
        const int nls = tid >> 2, kq = (tid & 3) * 16;
        const float* p0 = P + (size_t)(n0g + nls) * HCOLS + n0 + kq;
        const float* p1 = p0 + CSZ;
#pragma unroll
        for (int j4 = 0; j4 < 4; ++j4) {
            const float4 a = *(const float4*)(p0 + j4 * 4);
            const float4 b = *(const float4*)(p1 + j4 * 4);
            ah2[nls * 65 + kq + j4 * 4 + 0] = a.x + b.x;
            ah2[nls * 65 + kq + j4 * 4 + 1] = a.y + b.y;
            ah2[nls * 65 + kq + j4 * 4 + 2] = a.z + b.z;
            ah2[nls * 65 + kq + j4 * 4 + 3] = a.w + b.w;
        }
        __syncthreads();
    }

    // ================= phase B: gates + cell update ========================
    const int slab = my * 2 + z, n0g = slab * 64;
    const int nl = tid & 63, hq = tid >> 6;
#pragma unroll 1
    for (int bi = 0; bi < 2; ++bi) {
        const int b = nx2 * 2 + bi;
        const float ax0 = AX[(size_t)(n0g + nl) * XCOLS + (b * TT + t) * CIN + 0];
        const float ax1 = AX[(size_t)(n0g + nl) * XCOLS + (b * TT + t) * CIN + 1];
        float acc[8][4];
#pragma unroll
        for (int u = 0; u < 8; ++u) {
            const int h = hq * 8 + u;
#pragma unroll
            for (int q4 = 0; q4 < 4; ++q4)
                acc[u][q4] = bfl[h * 4 + q4] + ax0 * wxr[h * 4 + q4] + ax1 * wxr[128 + h * 4 + q4];
        }
        if (t > 0) {
            float ah_r[HH];
#pragma unroll
            for (int k = 0; k < HH; ++k) ah_r[k] = ah2[nl * 65 + bi * 32 + k];
#pragma unroll 4
            for (int k = 0; k < HH; ++k) {
                const float a = ah_r[k];
#pragma unroll
                for (int u = 0; u < 8; ++u) {
                    const float* wp = &whr[(k * HH + hq * 8 + u) * 4];
                    acc[u][0] += a * wp[0];
                    acc[u][1] += a * wp[1];
                    acc[u][2] += a * wp[2];
                    acc[u][3] += a * wp[3];
                }
            }
        }

        const size_t off = (size_t)(n0g + nl) * HCOLS + b * HH + hq * 8;
        float4 c0o = make_float4(0, 0, 0, 0), c1o = make_float4(0, 0, 0, 0);
        if (t > 0) { c0o = *(const float4*)(cst + off); c1o = *(const float4*)(cst + off + 4); }
        const float cold[8] = {c0o.x, c0o.y, c0o.z, c0o.w, c1o.x, c1o.y, c1o.z, c1o.w};
        float cn[8], hn[8];
#pragma unroll
        for (int u = 0; u < 8; ++u) {
            const float i_ = 1.0f / (1.0f + expf(-acc[u][0]));
            const float f_ = 1.0f / (1.0f + expf(-acc[u][1]));
            const float o_ = 1.0f / (1.0f + expf(-acc[u][2]));
            const float g_ = tanhf(acc[u][3]);
            const float c_t = f_ * cold[u] + i_ * g_;
            cn[u] = c_t;
            hn[u] = o_ * tanhf(c_t);
        }
        *(float4*)(cst + off)     = make_float4(cn[0], cn[1], cn[2], cn[3]);
        *(float4*)(cst + off + 4) = make_float4(cn[4], cn[5], cn[6], cn[7]);
#pragma unroll
        for (int u = 0; u < 8; ++u)
            hTw[(size_t)(b * HH + hq * 8 + u) * 2048 + n0g + nl] = (_Float16)hn[u];
        if (t == TT - 1) {
            *(float4*)(h32 + off)     = make_float4(hn[0], hn[1], hn[2], hn[3]);
            *(float4*)(h32 + off + 4) = make_float4(hn[4], hn[5], hn[6], hn[7]);
        }
    }
}

// ---------------------------------------------------------------------------
// Kernel 5: out[b][th][n] = bp[th] + sum_k h[n][b*H+k] * Wp[k][th]
// ---------------------------------------------------------------------------
__global__ __launch_bounds__(256) void head_kernel(const float* __restrict__ h,
                                                   const float* __restrict__ Wp,
                                                   const float* __restrict__ bp,
                                                   float* __restrict__ out) {
    const int idx = blockIdx.x * 256 + threadIdx.x;
    const int b = idx >> 11;
    const int n = idx & (NN - 1);
    float hv[HH];
    const float* hp = h + (size_t)n * HCOLS + b * HH;
#pragma unroll
    for (int k = 0; k < HH; ++k) hv[k] = hp[k];
#pragma unroll
    for (int th = 0; th < HOR; ++th) {
        float acc = bp[th];
#pragma unroll
        for (int k = 0; k < HH; ++k) acc += hv[k] * Wp[k * HOR + th];
        out[((size_t)b * HOR + th) * NN + n] = acc;
    }
}

// ---------------------------------------------------------------------------
extern "C" void kernel_launch(void* const* d_in, const int* in_sizes, int n_in,
                              void* d_out, int out_size, void* d_ws, size_t ws_size,
                              hipStream_t stream) {
    const float* x  = (const float*)d_in[0];
    const float* E1 = (const float*)d_in[1];
    const float* E2 = (const float*)d_in[2];
    const float* Wx = (const float*)d_in[3];
    const float* bx = (const float*)d_in[4];
    const float* Wh = (const float*)d_in[5];
    const float* bh = (const float*)d_in[6];
    const float* Wp = (const float*)d_in[7];
    const float* bp = (const float*)d_in[8];

    char* ws = (char*)d_ws;
    _Float16* A2  = (_Float16*)(ws);                    //  8 MB  [2048][2048]
    _Float16* Bx  = (_Float16*)(ws + ( 8ull << 20));    //  2 MB  [1024][2048]
    _Float16* hT0 = (_Float16*)(ws + (12ull << 20));    //  4 MB
    _Float16* hT1 = (_Float16*)(ws + (16ull << 20));    //  4 MB
    float* P    = (float*)(ws + (20ull << 20));         // 32 MB  (x: 4 slices; rec: 2)
    float* AX   = (float*)(ws + (52ull << 20));         //  8 MB
    float* cst  = (float*)(ws + (60ull << 20));         //  8 MB
    float* h32  = (float*)(ws + (68ull << 20));         //  8 MB
    float* Whr  = (float*)(ws + (76ull << 20));         // 16 KB
    float* Wxr  = (float*)(ws + (76ull << 20) + 65536);
    float* bfold= (float*)(ws + (76ull << 20) + 131072);
    unsigned* flags = (unsigned*)(ws + (77ull << 20));  // 256 flags, 64B stride

    hipMemsetAsync(flags, 0, 16384, stream);

    adj_softmax<<<NN, 256, 0, stream>>>(E1, E2, A2);
    transpose_x<<<(XCOLS * NN) / 256, 256, 0, stream>>>(x, Bx);
    prep_weights<<<1, 256, 0, stream>>>(Wx, bx, Wh, bh, Whr, Wxr, bfold);

    dim3 gg(HCOLS / 128, NN / 128, 4);   // 8 x 16 x 4 = 512 blocks
    gemm_x1<<<gg, 256, 0, stream>>>(A2, Bx, P);
    reduce_ax<<<(int)(CSZ / 4 / 256), 256, 0, stream>>>(P, AX);

    // 16 fused step launches; hT ping-pong: gemm reads buf[t&1], gate writes buf[(t+1)&1]
    for (int t = 0; t < TT; ++t) {
        const _Float16* hTr = (t & 1) ? hT1 : hT0;
        _Float16*       hTw = ((t + 1) & 1) ? hT1 : hT0;
        fused_step<<<512, 256, 0, stream>>>(A2, AX, P, Whr, Wxr, bfold,
                                            cst, h32, hTr, hTw, flags, t);
    }

    head_kernel<<<(BB * NN) / 256, 256, 0, stream>>>(h32, Wp, bp, (float*)d_out);
}